// Round 6
// baseline (137.169 us; speedup 1.0000x reference)
//
#include <hip/hip_runtime.h>
#include <hip/hip_bf16.h>

// Net_27358941675610: the 50-step scan collapses to its fixed point:
//   R   = 0.35*sigmoid((6/7)*(psp^T @ W_h^T + b_h))            [4096,2048]
//   out = 0.35*sigmoid(0.75*(R @ W_o^T + b_o) + 0.125*label)   [4096,512]
// Inputs fp32, output fp32. Internal: bf16 MFMA, fp32 acc.
// R21: T3-minimum 2-phase recipe (guide §5.5 T3 "Minimum 2-phase";
// m230/m248-verified) on BOTH gemms. All single-buffer configs measured
// ~43.5us (gemm1) / ~33us (gemm2) regardless of tile or occupancy:
// the naked stage->vmcnt(0)->barrier HBM latency per K-iter is the
// binder, not LDS throughput (R13 vs R17 falsified LDS theory).
// Change: LDS double-buffer + STAGE(t+1) issued BEFORE compute(t) +
// ONE vmcnt(0)+barrier per iter (at end). Fragment math / swizzle /
// epilogue byte-identical to proven R17 (gemm1) and R18 (gemm2).
// gemm1: 128x64, 4 waves, 48KB -> 3 blk/CU, grid 1024.
// gemm2: 64x64, 4 waves, BK=128 two-panel, 64KB -> 2 blk/CU, grid 512.

typedef __bf16 bf16_t;
typedef __bf16 bf16x8 __attribute__((ext_vector_type(8)));
typedef __bf16 bf16x4v __attribute__((ext_vector_type(4)));
typedef float f32x4 __attribute__((ext_vector_type(4)));
typedef float f32x16 __attribute__((ext_vector_type(16)));

#define GLD_TO_LDS16(gp, lp)                                            \
  __builtin_amdgcn_global_load_lds(                                     \
      (__attribute__((address_space(1))) void*)(void*)(gp),             \
      (__attribute__((address_space(3))) void*)(lp), 16, 0, 0)

#define END_OF_ITER_SYNC()                                              \
  asm volatile("s_waitcnt vmcnt(0)" ::: "memory");                      \
  __builtin_amdgcn_sched_barrier(0);                                    \
  __builtin_amdgcn_s_barrier();                                         \
  __builtin_amdgcn_sched_barrier(0);

// ---- prep: psp transpose+cvt AND both weight cvts, one kernel ------------
__global__ __launch_bounds__(256) void prep(
    const float* __restrict__ psp, bf16_t* __restrict__ pspT,
    const float4* __restrict__ w1, bf16x4v* __restrict__ o1, int n1,
    const float4* __restrict__ w2, bf16x4v* __restrict__ o2, int n2) {
  __shared__ float tile[64][65];
  const int tid = threadIdx.x;
  const int b = blockIdx.x;
  const int c0 = (b & 63) * 64;   // batch dim
  const int r0 = (b >> 6) * 64;   // in dim
  const int tx = tid & 63;
  const int ty = tid >> 6;
#pragma unroll
  for (int i = 0; i < 16; ++i) {
    const int r = ty + i * 4;
    tile[r][tx] = psp[(size_t)(r0 + r) * 4096 + c0 + tx];
  }
  const int base = b * 768 + tid;
#pragma unroll
  for (int i = 0; i < 3; ++i) {
    const int idx = base + i * 256;
    const float4 v = (idx < n1) ? w1[idx] : w2[idx - n1];
    bf16x4v o;
    o.x = (bf16_t)v.x; o.y = (bf16_t)v.y; o.z = (bf16_t)v.z; o.w = (bf16_t)v.w;
    if (idx < n1) o1[idx] = o;
    else if (idx - n1 < n2) o2[idx - n1] = o;
  }
  __syncthreads();
#pragma unroll
  for (int i = 0; i < 16; ++i) {
    const int r = ty + i * 4;
    pspT[(size_t)(c0 + r) * 1024 + r0 + tx] = (bf16_t)tile[tx][r];
  }
}

// ---- GEMM1: R(bf16) = 0.35*sigmoid(6/7*(A @ Bt^T + bias)) ----------------
// R17 math + 2-phase dbuf. mfma_f32_32x32x16_bf16. 128x64 tile, 4 waves
// of 64x32, BK=64, LDS 2x24KB=48KB -> 3 blk/CU, grid (32,32)=1024.
__global__ __launch_bounds__(256, 3) void gemm1_nt(
    const bf16_t* __restrict__ A, const bf16_t* __restrict__ Bt,
    const float* __restrict__ bias, bf16_t* __restrict__ C,
    int M, int N, int K) {
  constexpr int BK = 64;
  __shared__ __align__(16) bf16_t sA[2][128 * BK];  // 2 x 16 KB
  __shared__ __align__(16) bf16_t sB[2][64 * BK];   // 2 x  8 KB

  const int tid = threadIdx.x;
  const int wave = tid >> 6;  // 0..3
  const int lane = tid & 63;
  const int bm = blockIdx.x * 128;
  const int bn = blockIdx.y * 64;
  const int wm = (wave & 1) * 64;   // 2 M-positions
  const int wn = (wave >> 1) * 32;  // 2 N-positions

  f32x16 acc[2] = {};

  const int srow8 = lane >> 3;
  const int gseg = (lane & 7) ^ srow8;  // pre-swizzled global k-segment
  const bf16_t* Ag = A + (size_t)(bm + wave * 32 + srow8) * K + gseg * 8;
  const bf16_t* Bg = Bt + (size_t)(bn + wave * 16 + srow8) * K + gseg * 8;
  const int dstA = wave * 2048;  // wave*32 rows
  const int dstB = wave * 1024;  // wave*16 rows

  const int col = lane & 31;
  const int g = lane >> 5;
  const int NT = K / BK;  // 16

#define STAGE1(bufi, t)                                                \
  {                                                                    \
    bf16_t* dA_ = &sA[bufi][dstA];                                     \
    bf16_t* dB_ = &sB[bufi][dstB];                                     \
    const bf16_t* sa_ = Ag + (size_t)(t) * BK;                         \
    const bf16_t* sb_ = Bg + (size_t)(t) * BK;                         \
    _Pragma("unroll") for (int c_ = 0; c_ < 4; ++c_)                   \
        GLD_TO_LDS16(sa_ + (size_t)(c_ * 8) * K, dA_ + c_ * 512);      \
    _Pragma("unroll") for (int c_ = 0; c_ < 2; ++c_)                   \
        GLD_TO_LDS16(sb_ + (size_t)(c_ * 8) * K, dB_ + c_ * 512);      \
  }

  // prologue: stage tile 0, drain, barrier.
  STAGE1(0, 0);
  END_OF_ITER_SYNC();

  int cur = 0;
  for (int t = 0; t < NT; ++t) {
    // issue next tile's loads FIRST; they land while we compute tile t.
    if (t + 1 < NT) STAGE1(cur ^ 1, t + 1);

    const bf16_t* a_ = sA[cur];
    const bf16_t* b_ = sB[cur];
#pragma unroll
    for (int ks = 0; ks < 4; ++ks) {
      const int q = ks * 2 + g;
      bf16x8 av[2], bv;
#pragma unroll
      for (int i = 0; i < 2; ++i) {
        const int rr = wm + i * 32 + col;
        av[i] = *(const bf16x8*)(a_ + rr * BK + ((q ^ (rr & 7)) * 8));
      }
      {
        const int rr = wn + col;
        bv = *(const bf16x8*)(b_ + rr * BK + ((q ^ (rr & 7)) * 8));
      }
      __builtin_amdgcn_s_setprio(1);
#pragma unroll
      for (int i = 0; i < 2; ++i)
        acc[i] = __builtin_amdgcn_mfma_f32_32x32x16_bf16(av[i], bv, acc[i],
                                                         0, 0, 0);
      __builtin_amdgcn_s_setprio(0);
    }

    if (t + 1 < NT) {
      END_OF_ITER_SYNC();
      cur ^= 1;
    }
  }
#undef STAGE1

  // epilogue: col = lane&31, row = (r&3) + 8*(r>>2) + 4*(lane>>5) [m74/m101]
  const int rbase = 4 * g;
  const int gn = bn + wn + col;
  const float bj = bias[gn];
#pragma unroll
  for (int i = 0; i < 2; ++i) {
#pragma unroll
    for (int r = 0; r < 16; ++r) {
      const int gm = bm + wm + i * 32 + (r & 3) + 8 * (r >> 2) + rbase;
      const float z = 0.8571428571428571f * (acc[i][r] + bj);
      C[(size_t)gm * N + gn] = (bf16_t)(0.35f / (1.0f + __expf(-z)));
    }
  }
}

// ---- GEMM2: out(fp32) = 0.35*sigmoid(0.75*(R @ Wo^T + b_o) + 0.125*lbl) --
// R18 math + 2-phase dbuf. 64x64 tile, 4 waves of 32x32 (2x2 frags of
// 16x16), BK=128 as two BK=64 panels. LDS 2x32KB=64KB -> 2 blk/CU,
// grid (64,8)=512 = exactly 2/CU.
__global__ __launch_bounds__(256, 2) void gemm2_nt(
    const bf16_t* __restrict__ A, const bf16_t* __restrict__ Bt,
    const float* __restrict__ bias, const float* __restrict__ lbl,
    float* __restrict__ out, int M, int N, int K) {
  __shared__ __align__(16) bf16_t sA[2][2][64 * 64];  // 2 x 16 KB
  __shared__ __align__(16) bf16_t sB[2][2][64 * 64];  // 2 x 16 KB

  const int tid = threadIdx.x;
  const int wave = tid >> 6;
  const int lane = tid & 63;
  const int bm = blockIdx.x * 64;
  const int bn = blockIdx.y * 64;
  const int wm = (wave & 1) * 32;
  const int wn = (wave >> 1) * 32;

  f32x4 acc[2][2] = {};

  const int srow8 = lane >> 3;
  const int gseg = (lane & 7) ^ srow8;  // pre-swizzled global k-segment
  const bf16_t* Ag = A + (size_t)(bm + wave * 16 + srow8) * K + gseg * 8;
  const bf16_t* Bg = Bt + (size_t)(bn + wave * 16 + srow8) * K + gseg * 8;
  const int dst = wave * 1024;  // 16 rows * 64 elems per wave, per panel

  const int fr = lane & 15;
  const int qh = lane >> 4;
  const int NT = K / 128;  // 16

#define STAGE2(bufi, t)                                                \
  {                                                                    \
    const int k0_ = (t) * 128;                                         \
    _Pragma("unroll") for (int p_ = 0; p_ < 2; ++p_) {                 \
      _Pragma("unroll") for (int c_ = 0; c_ < 2; ++c_) {               \
        GLD_TO_LDS16(Ag + k0_ + p_ * 64 + (size_t)(c_ * 8) * K,        \
                     sA[bufi][p_] + dst + c_ * 512);                   \
        GLD_TO_LDS16(Bg + k0_ + p_ * 64 + (size_t)(c_ * 8) * K,        \
                     sB[bufi][p_] + dst + c_ * 512);                   \
      }                                                                \
    }                                                                  \
  }

  STAGE2(0, 0);
  END_OF_ITER_SYNC();

  int cur = 0;
  for (int t = 0; t < NT; ++t) {
    if (t + 1 < NT) STAGE2(cur ^ 1, t + 1);

    const bf16_t* a0 = sA[cur][0];
    const bf16_t* a1 = sA[cur][1];
    const bf16_t* b0 = sB[cur][0];
    const bf16_t* b1 = sB[cur][1];
#pragma unroll
    for (int ks = 0; ks < 4; ++ks) {
      const int q = ks * 4 + qh;   // granule 0..15 across BK=128
      const int pnl = ks >> 1;     // panel (wave-uniform)
      const int q2 = q & 7;        // granule within panel
      const bf16_t* aP = pnl ? a1 : a0;
      const bf16_t* bP = pnl ? b1 : b0;
      bf16x8 av[2], bv[2];
#pragma unroll
      for (int i = 0; i < 2; ++i) {
        const int ra = wm + i * 16 + fr;
        av[i] = *(const bf16x8*)(aP + ra * 64 + ((q2 ^ (ra & 7)) * 8));
      }
#pragma unroll
      for (int j = 0; j < 2; ++j) {
        const int rb = wn + j * 16 + fr;
        bv[j] = *(const bf16x8*)(bP + rb * 64 + ((q2 ^ (rb & 7)) * 8));
      }
      __builtin_amdgcn_s_setprio(1);
#pragma unroll
      for (int i = 0; i < 2; ++i)
#pragma unroll
        for (int j = 0; j < 2; ++j)
          acc[i][j] = __builtin_amdgcn_mfma_f32_16x16x32_bf16(
              av[i], bv[j], acc[i][j], 0, 0, 0);
      __builtin_amdgcn_s_setprio(0);
    }

    if (t + 1 < NT) {
      END_OF_ITER_SYNC();
      cur ^= 1;
    }
  }
#undef STAGE2

  // epilogue: col = lane&15, row = (lane>>4)*4 + reg [m89/m91]
  const int cm0 = qh * 4;
#pragma unroll
  for (int j = 0; j < 2; ++j) {
    const int gn = bn + wn + j * 16 + fr;
    const float bj = bias[gn];
#pragma unroll
    for (int i = 0; i < 2; ++i) {
#pragma unroll
      for (int r = 0; r < 4; ++r) {
        const int gm = bm + wm + i * 16 + cm0 + r;
        const float z =
            0.75f * (acc[i][j][r] + bj) + 0.125f * lbl[(size_t)gm * N + gn];
        out[(size_t)gm * N + gn] = 0.35f / (1.0f + __expf(-z));
      }
    }
  }
}

extern "C" void kernel_launch(void* const* d_in, const int* in_sizes, int n_in,
                              void* d_out, int out_size, void* d_ws, size_t ws_size,
                              hipStream_t stream) {
  constexpr int IN = 1024, HID = 2048, OUT = 512, B = 4096;
  const float* psp = (const float*)d_in[0];   // [IN, B]
  const float* lbl = (const float*)d_in[1];   // [B, OUT]
  const float* W_h = (const float*)d_in[2];   // [HID, IN]
  const float* b_h = (const float*)d_in[3];   // [HID]
  const float* W_o = (const float*)d_in[4];   // [OUT, HID]
  const float* b_o = (const float*)d_in[5];   // [OUT]
  float* out = (float*)d_out;                 // [B, OUT] fp32

  bf16_t* Whb = (bf16_t*)d_ws;                 // [HID, IN]  4 MB
  bf16_t* Wob = Whb + (size_t)HID * IN;        // [OUT, HID] 2 MB
  bf16_t* pspT = Wob + (size_t)OUT * HID;      // [B, IN]    8 MB
  bf16_t* Rm = pspT + (size_t)B * IN;          // [B, HID]  16 MB

  prep<<<1024, 256, 0, stream>>>(
      psp, pspT, (const float4*)W_h, (bf16x4v*)Whb, HID * IN / 4,
      (const float4*)W_o, (bf16x4v*)Wob, OUT * HID / 4);
  gemm1_nt<<<dim3(B / 128, HID / 64), 256, 0, stream>>>(
      pspT, Whb, b_h, Rm, B, HID, IN);
  gemm2_nt<<<dim3(B / 64, OUT / 64), 256, 0, stream>>>(
      Rm, Wob, b_o, lbl, out, B, OUT, HID);
}

// Round 7
// 126.970 us; speedup vs baseline: 1.0803x; 1.0803x over previous
//
#include <hip/hip_runtime.h>
#include <hip/hip_bf16.h>

// Net_27358941675610: the 50-step scan collapses to its fixed point:
//   R   = 0.35*sigmoid((6/7)*(psp^T @ W_h^T + b_h))            [4096,2048]
//   out = 0.35*sigmoid(0.75*(R @ W_o^T + b_o) + 0.125*label)   [4096,512]
// Inputs fp32, output fp32. Internal: bf16 MFMA, fp32 acc.
// R22: iteration-count reduction via multi-panel BK (the ONLY lever that
// measurably helped this session: R18's gemm2 BK 64->128 = -11%). Five
// scheduling attempts (R16/R19/R20/R21) all regressed; data shows a fixed
// ~2400+ cyc per-iteration latency insensitive to buffering, so halve the
// iteration count at constant volume with byte-identical per-panel math.
// gemm1: 128x128 tile, BK=128 (2 panels), NT=8, LDS 64KB, 2 blk/CU,
//        grid (32,16)=512 = one full-device round. R15/R16-proven frags.
// gemm2: R18 + 4 panels (BK=256), NT=8, LDS 64KB, 2 blk/CU, grid 512.
// Single-buffer 2-barrier loop kept (proven least-bad). prep unchanged.

typedef __bf16 bf16_t;
typedef __bf16 bf16x8 __attribute__((ext_vector_type(8)));
typedef __bf16 bf16x4v __attribute__((ext_vector_type(4)));
typedef float f32x4 __attribute__((ext_vector_type(4)));
typedef float f32x16 __attribute__((ext_vector_type(16)));

#define GLD_TO_LDS16(gp, lp)                                            \
  __builtin_amdgcn_global_load_lds(                                     \
      (__attribute__((address_space(1))) void*)(void*)(gp),             \
      (__attribute__((address_space(3))) void*)(lp), 16, 0, 0)

// ---- prep: psp transpose+cvt AND both weight cvts, one kernel ------------
__global__ __launch_bounds__(256) void prep(
    const float* __restrict__ psp, bf16_t* __restrict__ pspT,
    const float4* __restrict__ w1, bf16x4v* __restrict__ o1, int n1,
    const float4* __restrict__ w2, bf16x4v* __restrict__ o2, int n2) {
  __shared__ float tile[64][65];
  const int tid = threadIdx.x;
  const int b = blockIdx.x;
  const int c0 = (b & 63) * 64;   // batch dim
  const int r0 = (b >> 6) * 64;   // in dim
  const int tx = tid & 63;
  const int ty = tid >> 6;
#pragma unroll
  for (int i = 0; i < 16; ++i) {
    const int r = ty + i * 4;
    tile[r][tx] = psp[(size_t)(r0 + r) * 4096 + c0 + tx];
  }
  const int base = b * 768 + tid;
#pragma unroll
  for (int i = 0; i < 3; ++i) {
    const int idx = base + i * 256;
    const float4 v = (idx < n1) ? w1[idx] : w2[idx - n1];
    bf16x4v o;
    o.x = (bf16_t)v.x; o.y = (bf16_t)v.y; o.z = (bf16_t)v.z; o.w = (bf16_t)v.w;
    if (idx < n1) o1[idx] = o;
    else if (idx - n1 < n2) o2[idx - n1] = o;
  }
  __syncthreads();
#pragma unroll
  for (int i = 0; i < 16; ++i) {
    const int r = ty + i * 4;
    pspT[(size_t)(c0 + r) * 1024 + r0 + tx] = (bf16_t)tile[tx][r];
  }
}

// ---- GEMM1: R(bf16) = 0.35*sigmoid(6/7*(A @ Bt^T + bias)) ----------------
// mfma_f32_32x32x16_bf16. 128x128 tile, 4 waves of 64x64 (2x2 of 32x32),
// BK=128 as TWO proven 64-panels, NT=8. LDS 64KB single-buffer ->
// 2 blk/CU, grid (32,16)=512 = exactly one device round.
__global__ __launch_bounds__(256, 2) void gemm1_nt(
    const bf16_t* __restrict__ A, const bf16_t* __restrict__ Bt,
    const float* __restrict__ bias, bf16_t* __restrict__ C,
    int M, int N, int K) {
  __shared__ __align__(16) bf16_t sA[2][128 * 64];  // 2 panels x 16 KB
  __shared__ __align__(16) bf16_t sB[2][128 * 64];  // 2 panels x 16 KB

  const int tid = threadIdx.x;
  const int wave = tid >> 6;  // 0..3
  const int lane = tid & 63;
  const int bm = blockIdx.x * 128;
  const int bn = blockIdx.y * 128;
  const int wm = (wave & 1) * 64;
  const int wn = (wave >> 1) * 64;

  f32x16 acc[2][2] = {};

  const int srow8 = lane >> 3;
  const int gseg = (lane & 7) ^ srow8;  // pre-swizzled global k-segment
  const bf16_t* Ag = A + (size_t)(bm + wave * 32 + srow8) * K + gseg * 8;
  const bf16_t* Bg = Bt + (size_t)(bn + wave * 32 + srow8) * K + gseg * 8;
  const int dst = wave * 2048;  // 32 rows * 64 elems, per panel

  const int col = lane & 31;
  const int g = lane >> 5;
  const int NT = K / 128;  // 8

  for (int t = 0; t < NT; ++t) {
    const int k0 = t * 128;
#pragma unroll
    for (int p = 0; p < 2; ++p) {
#pragma unroll
      for (int c = 0; c < 4; ++c) {
        GLD_TO_LDS16(Ag + k0 + p * 64 + (size_t)(c * 8) * K,
                     sA[p] + dst + c * 512);
        GLD_TO_LDS16(Bg + k0 + p * 64 + (size_t)(c * 8) * K,
                     sB[p] + dst + c * 512);
      }
    }
    __syncthreads();

#pragma unroll
    for (int p = 0; p < 2; ++p) {
#pragma unroll
      for (int ks = 0; ks < 4; ++ks) {
        const int q = ks * 2 + g;
        bf16x8 av[2], bv[2];
#pragma unroll
        for (int i = 0; i < 2; ++i) {
          const int rr = wm + i * 32 + col;
          av[i] = *(const bf16x8*)(sA[p] + rr * 64 + ((q ^ (rr & 7)) * 8));
        }
#pragma unroll
        for (int j = 0; j < 2; ++j) {
          const int rr = wn + j * 32 + col;
          bv[j] = *(const bf16x8*)(sB[p] + rr * 64 + ((q ^ (rr & 7)) * 8));
        }
#pragma unroll
        for (int i = 0; i < 2; ++i)
#pragma unroll
          for (int j = 0; j < 2; ++j)
            acc[i][j] = __builtin_amdgcn_mfma_f32_32x32x16_bf16(
                av[i], bv[j], acc[i][j], 0, 0, 0);
      }
    }
    __syncthreads();
  }

  // epilogue: col = lane&31, row = (r&3) + 8*(r>>2) + 4*(lane>>5) [m74/m101]
  const int rbase = 4 * g;
#pragma unroll
  for (int j = 0; j < 2; ++j) {
    const int gn = bn + wn + j * 32 + col;
    const float bj = bias[gn];
#pragma unroll
    for (int i = 0; i < 2; ++i) {
#pragma unroll
      for (int r = 0; r < 16; ++r) {
        const int gm = bm + wm + i * 32 + (r & 3) + 8 * (r >> 2) + rbase;
        const float z = 0.8571428571428571f * (acc[i][j][r] + bj);
        C[(size_t)gm * N + gn] = (bf16_t)(0.35f / (1.0f + __expf(-z)));
      }
    }
  }
}

// ---- GEMM2: out(fp32) = 0.35*sigmoid(0.75*(R @ Wo^T + b_o) + 0.125*lbl) --
// R18 + 4 panels: 64x64 tile, 4 waves of 32x32 (2x2 frags of 16x16),
// BK=256 as FOUR proven 64-panels, NT=8. LDS 64KB -> 2 blk/CU, grid 512.
__global__ __launch_bounds__(256, 2) void gemm2_nt(
    const bf16_t* __restrict__ A, const bf16_t* __restrict__ Bt,
    const float* __restrict__ bias, const float* __restrict__ lbl,
    float* __restrict__ out, int M, int N, int K) {
  __shared__ __align__(16) bf16_t sA[4][64 * 64];  // 4 panels x 8 KB
  __shared__ __align__(16) bf16_t sB[4][64 * 64];  // 4 panels x 8 KB

  const int tid = threadIdx.x;
  const int wave = tid >> 6;
  const int lane = tid & 63;
  const int bm = blockIdx.x * 64;
  const int bn = blockIdx.y * 64;
  const int wm = (wave & 1) * 32;
  const int wn = (wave >> 1) * 32;

  f32x4 acc[2][2] = {};

  const int srow8 = lane >> 3;
  const int gseg = (lane & 7) ^ srow8;  // pre-swizzled global k-segment
  const bf16_t* Ag = A + (size_t)(bm + wave * 16 + srow8) * K + gseg * 8;
  const bf16_t* Bg = Bt + (size_t)(bn + wave * 16 + srow8) * K + gseg * 8;
  const int dst = wave * 1024;  // 16 rows * 64 elems per wave, per panel

  const int fr = lane & 15;
  const int qh = lane >> 4;
  const int NT = K / 256;  // 8

  for (int t = 0; t < NT; ++t) {
    const int k0 = t * 256;
#pragma unroll
    for (int p = 0; p < 4; ++p) {
#pragma unroll
      for (int c = 0; c < 2; ++c) {
        GLD_TO_LDS16(Ag + k0 + p * 64 + (size_t)(c * 8) * K,
                     sA[p] + dst + c * 512);
        GLD_TO_LDS16(Bg + k0 + p * 64 + (size_t)(c * 8) * K,
                     sB[p] + dst + c * 512);
      }
    }
    __syncthreads();

#pragma unroll
    for (int ks = 0; ks < 8; ++ks) {
      const int pnl = ks >> 1;           // panel (wave-uniform, compile-time)
      const int q2 = (ks * 4 + qh) & 7;  // granule within panel
      bf16x8 av[2], bv[2];
#pragma unroll
      for (int i = 0; i < 2; ++i) {
        const int ra = wm + i * 16 + fr;
        av[i] = *(const bf16x8*)(sA[pnl] + ra * 64 + ((q2 ^ (ra & 7)) * 8));
      }
#pragma unroll
      for (int j = 0; j < 2; ++j) {
        const int rb = wn + j * 16 + fr;
        bv[j] = *(const bf16x8*)(sB[pnl] + rb * 64 + ((q2 ^ (rb & 7)) * 8));
      }
#pragma unroll
      for (int i = 0; i < 2; ++i)
#pragma unroll
        for (int j = 0; j < 2; ++j)
          acc[i][j] = __builtin_amdgcn_mfma_f32_16x16x32_bf16(
              av[i], bv[j], acc[i][j], 0, 0, 0);
    }
    __syncthreads();
  }

  // epilogue: col = lane&15, row = (lane>>4)*4 + reg [m89/m91]
  const int cm0 = qh * 4;
#pragma unroll
  for (int j = 0; j < 2; ++j) {
    const int gn = bn + wn + j * 16 + fr;
    const float bj = bias[gn];
#pragma unroll
    for (int i = 0; i < 2; ++i) {
#pragma unroll
      for (int r = 0; r < 4; ++r) {
        const int gm = bm + wm + i * 16 + cm0 + r;
        const float z =
            0.75f * (acc[i][j][r] + bj) + 0.125f * lbl[(size_t)gm * N + gn];
        out[(size_t)gm * N + gn] = 0.35f / (1.0f + __expf(-z));
      }
    }
  }
}

extern "C" void kernel_launch(void* const* d_in, const int* in_sizes, int n_in,
                              void* d_out, int out_size, void* d_ws, size_t ws_size,
                              hipStream_t stream) {
  constexpr int IN = 1024, HID = 2048, OUT = 512, B = 4096;
  const float* psp = (const float*)d_in[0];   // [IN, B]
  const float* lbl = (const float*)d_in[1];   // [B, OUT]
  const float* W_h = (const float*)d_in[2];   // [HID, IN]
  const float* b_h = (const float*)d_in[3];   // [HID]
  const float* W_o = (const float*)d_in[4];   // [OUT, HID]
  const float* b_o = (const float*)d_in[5];   // [OUT]
  float* out = (float*)d_out;                 // [B, OUT] fp32

  bf16_t* Whb = (bf16_t*)d_ws;                 // [HID, IN]  4 MB
  bf16_t* Wob = Whb + (size_t)HID * IN;        // [OUT, HID] 2 MB
  bf16_t* pspT = Wob + (size_t)OUT * HID;      // [B, IN]    8 MB
  bf16_t* Rm = pspT + (size_t)B * IN;          // [B, HID]  16 MB

  prep<<<1024, 256, 0, stream>>>(
      psp, pspT, (const float4*)W_h, (bf16x4v*)Whb, HID * IN / 4,
      (const float4*)W_o, (bf16x4v*)Wob, OUT * HID / 4);
  gemm1_nt<<<dim3(B / 128, HID / 128), 256, 0, stream>>>(
      pspT, Whb, b_h, Rm, B, HID, IN);
  gemm2_nt<<<dim3(B / 64, OUT / 64), 256, 0, stream>>>(
      Rm, Wob, b_o, lbl, out, B, OUT, HID);
}

// Round 8
// 117.265 us; speedup vs baseline: 1.1697x; 1.0828x over previous
//
#include <hip/hip_runtime.h>
#include <hip/hip_bf16.h>

// Net_27358941675610: the 50-step scan collapses to its fixed point:
//   R   = 0.35*sigmoid((6/7)*(psp^T @ W_h^T + b_h))            [4096,2048]
//   out = 0.35*sigmoid(0.75*(R @ W_o^T + b_o) + 0.125*label)   [4096,512]
// R23: gemm1 -> MX-fp8 (e4m3, unit scales) mfma_scale_32x32x64.
// Rationale: 7 structural variants of bf16 gemm1 all plateau ~40-43us with
// every pipe <20% busy; the scheduling axis is exhausted. learn_hip m148:
// the same 2-barrier structure gained +78% from MX-fp8 (912->1628 TF) by
// collapsing per-iter instruction counts (here: 48 ds_read + 32 MFMA ->
// 32 ds_read + 16 MFMA at 2x rate per wave-iter). Unit scales 0x7F7F7F7F
// make the scale-operand layout irrelevant (2^0 whichever byte is read).
// LDS: two half-K planes of 128B rows == byte-identical addressing to the
// proven bf16 two-panel scheme (same gld_lds, same XOR swizzle). BK=256
// fp8, NT=4, 64KB LDS, 2 blk/CU, grid (32,16)=512. R/gemm2 stay bf16
// (error isolation); prep emits fp8 pspT/W_h via v_cvt_pk_fp8_f32.
// gemm2 = R22 verbatim (64x64, BK=256 four-panel, NT=8).

typedef __bf16 bf16_t;
typedef __bf16 bf16x8 __attribute__((ext_vector_type(8)));
typedef __bf16 bf16x4v __attribute__((ext_vector_type(4)));
typedef float f32x4 __attribute__((ext_vector_type(4)));
typedef float f32x16 __attribute__((ext_vector_type(16)));
typedef int i32x4 __attribute__((ext_vector_type(4)));
typedef int i32x8 __attribute__((ext_vector_type(8)));

#define GLD_TO_LDS16(gp, lp)                                            \
  __builtin_amdgcn_global_load_lds(                                     \
      (__attribute__((address_space(1))) void*)(void*)(gp),             \
      (__attribute__((address_space(3))) void*)(lp), 16, 0, 0)

__device__ inline int pk4_fp8(float x, float y, float z, float w) {
  int lo = __builtin_amdgcn_cvt_pk_fp8_f32(x, y, 0, false);   // bytes 0,1
  return __builtin_amdgcn_cvt_pk_fp8_f32(z, w, lo, true);     // bytes 2,3
}

// ---- prep: psp transpose->fp8, W_h->fp8, W_o->bf16, one kernel -----------
__global__ __launch_bounds__(256) void prep(
    const float* __restrict__ psp, unsigned char* __restrict__ pspT8,
    const float4* __restrict__ wh, int* __restrict__ wh8,
    const float4* __restrict__ wo, bf16x4v* __restrict__ wob) {
  __shared__ float tile[64][65];
  const int tid = threadIdx.x;
  const int b = blockIdx.x;
  const int c0 = (b & 63) * 64;   // batch dim base
  const int r0 = (b >> 6) * 64;   // in dim base
  const int tx = tid & 63;
  const int ty = tid >> 6;
#pragma unroll
  for (int i = 0; i < 16; ++i) {
    const int r = ty + i * 4;
    tile[r][tx] = psp[(size_t)(r0 + r) * 4096 + c0 + tx];  // tile[in][batch]
  }
  // W_h -> fp8: 524288 float4 total = 1024 blocks * 512
  {
    const int i1 = b * 512 + tid;
#pragma unroll
    for (int u = 0; u < 2; ++u) {
      const int idx = i1 + u * 256;
      const float4 v = wh[idx];
      wh8[idx] = pk4_fp8(v.x, v.y, v.z, v.w);
    }
  }
  // W_o -> bf16: 262144 float4 total = 1024 blocks * 256
  {
    const int i2 = b * 256 + tid;
    const float4 v = wo[i2];
    bf16x4v o;
    o.x = (bf16_t)v.x; o.y = (bf16_t)v.y; o.z = (bf16_t)v.z; o.w = (bf16_t)v.w;
    wob[i2] = o;
  }
  __syncthreads();
  // transpose out as fp8: thread packs 4 consecutive in-dim elems
  const int brow0 = tid >> 4;        // batch-local row base
  const int c4 = (tid & 15) * 4;     // in-local col base
#pragma unroll
  for (int i = 0; i < 4; ++i) {
    const int brow = brow0 + i * 16;
    const int packed = pk4_fp8(tile[c4][brow], tile[c4 + 1][brow],
                               tile[c4 + 2][brow], tile[c4 + 3][brow]);
    *(int*)(pspT8 + (size_t)(c0 + brow) * 1024 + r0 + c4) = packed;
  }
}

// ---- GEMM1: R(bf16) = 0.35*sigmoid(6/7*(A @ Bt^T + bias)), MX-fp8 -------
// mfma_scale_f32_32x32x64_f8f6f4, unit scales. 128x128 tile, 4 waves of
// 64x64 (2x2 of 32x32). BK=256 fp8 as two 128B half-K planes, NT=4.
// LDS 64KB single-buffer -> 2 blk/CU, grid (32,16)=512.
__global__ __launch_bounds__(256, 2) void gemm1_nt(
    const unsigned char* __restrict__ A8, const unsigned char* __restrict__ B8,
    const float* __restrict__ bias, bf16_t* __restrict__ C,
    int M, int N, int K) {  // K = 1024 elems = 1024 bytes/row
  __shared__ __align__(16) unsigned char sA[2][128 * 128];  // 2 planes x 16KB
  __shared__ __align__(16) unsigned char sB[2][128 * 128];

  const int tid = threadIdx.x;
  const int wave = tid >> 6;  // 0..3
  const int lane = tid & 63;
  const int bm = blockIdx.x * 128;
  const int bn = blockIdx.y * 128;
  const int wm = (wave & 1) * 64;
  const int wn = (wave >> 1) * 64;

  f32x16 acc[2][2] = {};

  const int srow8 = lane >> 3;
  const int gseg = (lane & 7) ^ srow8;  // pre-swizzled global 16B-segment
  const unsigned char* Ag =
      A8 + (size_t)(bm + wave * 32 + srow8) * 1024 + gseg * 16;
  const unsigned char* Bg =
      B8 + (size_t)(bn + wave * 32 + srow8) * 1024 + gseg * 16;
  const int dst = wave * 4096;  // 32 rows * 128 B per wave, per plane

  const int col = lane & 31;
  const int g = lane >> 5;

  for (int t = 0; t < 4; ++t) {  // NT = 1024/256
    const int kb = t * 256;      // k-byte base of this tile
#pragma unroll
    for (int h = 0; h < 2; ++h) {     // half-K plane (128 B)
#pragma unroll
      for (int c = 0; c < 4; ++c) {   // 8-row chunks
        GLD_TO_LDS16(Ag + kb + h * 128 + (size_t)(c * 8) * 1024,
                     sA[h] + dst + c * 1024);
        GLD_TO_LDS16(Bg + kb + h * 128 + (size_t)(c * 8) * 1024,
                     sB[h] + dst + c * 1024);
      }
    }
    __syncthreads();

#pragma unroll
    for (int p = 0; p < 4; ++p) {  // k64-steps within BK=256
      const int h = p >> 1;
      const int s0 = (p & 1) * 4 + 2 * g;  // lane-group's first 16B segment
      i32x8 av[2], bv[2];
#pragma unroll
      for (int i = 0; i < 2; ++i) {
        const int rr = wm + i * 32 + col;
        const unsigned char* base = sA[h] + rr * 128;
        const i32x4 lo = *(const i32x4*)(base + ((s0 ^ (rr & 7)) * 16));
        const i32x4 hi = *(const i32x4*)(base + (((s0 + 1) ^ (rr & 7)) * 16));
        av[i] = __builtin_shufflevector(lo, hi, 0, 1, 2, 3, 4, 5, 6, 7);
      }
#pragma unroll
      for (int j = 0; j < 2; ++j) {
        const int rr = wn + j * 32 + col;
        const unsigned char* base = sB[h] + rr * 128;
        const i32x4 lo = *(const i32x4*)(base + ((s0 ^ (rr & 7)) * 16));
        const i32x4 hi = *(const i32x4*)(base + (((s0 + 1) ^ (rr & 7)) * 16));
        bv[j] = __builtin_shufflevector(lo, hi, 0, 1, 2, 3, 4, 5, 6, 7);
      }
      __builtin_amdgcn_s_setprio(1);
#pragma unroll
      for (int i = 0; i < 2; ++i)
#pragma unroll
        for (int j = 0; j < 2; ++j)
          acc[i][j] = __builtin_amdgcn_mfma_scale_f32_32x32x64_f8f6f4(
              av[i], bv[j], acc[i][j], 0, 0,          // cbsz=fp8, blgp=fp8
              0, 0x7F7F7F7F, 0, 0x7F7F7F7F);          // unit scales (2^0)
      __builtin_amdgcn_s_setprio(0);
    }
    __syncthreads();
  }

  // epilogue: col = lane&31, row = (r&3) + 8*(r>>2) + 4*(lane>>5) [m74/m101]
  const int rbase = 4 * g;
#pragma unroll
  for (int j = 0; j < 2; ++j) {
    const int gn = bn + wn + j * 32 + col;
    const float bj = bias[gn];
#pragma unroll
    for (int i = 0; i < 2; ++i) {
#pragma unroll
      for (int r = 0; r < 16; ++r) {
        const int gm = bm + wm + i * 32 + (r & 3) + 8 * (r >> 2) + rbase;
        const float z = 0.8571428571428571f * (acc[i][j][r] + bj);
        C[(size_t)gm * N + gn] = (bf16_t)(0.35f / (1.0f + __expf(-z)));
      }
    }
  }
}

// ---- GEMM2: out(fp32) = 0.35*sigmoid(0.75*(R @ Wo^T + b_o) + 0.125*lbl) --
// R22 verbatim: 64x64 tile, 4 waves of 32x32 (2x2 frags of 16x16),
// BK=256 as FOUR proven 64-panels, NT=8. LDS 64KB -> 2 blk/CU, grid 512.
__global__ __launch_bounds__(256, 2) void gemm2_nt(
    const bf16_t* __restrict__ A, const bf16_t* __restrict__ Bt,
    const float* __restrict__ bias, const float* __restrict__ lbl,
    float* __restrict__ out, int M, int N, int K) {
  __shared__ __align__(16) bf16_t sA[4][64 * 64];  // 4 panels x 8 KB
  __shared__ __align__(16) bf16_t sB[4][64 * 64];  // 4 panels x 8 KB

  const int tid = threadIdx.x;
  const int wave = tid >> 6;
  const int lane = tid & 63;
  const int bm = blockIdx.x * 64;
  const int bn = blockIdx.y * 64;
  const int wm = (wave & 1) * 32;
  const int wn = (wave >> 1) * 32;

  f32x4 acc[2][2] = {};

  const int srow8 = lane >> 3;
  const int gseg = (lane & 7) ^ srow8;
  const bf16_t* Ag = A + (size_t)(bm + wave * 16 + srow8) * K + gseg * 8;
  const bf16_t* Bg = Bt + (size_t)(bn + wave * 16 + srow8) * K + gseg * 8;
  const int dst = wave * 1024;

  const int fr = lane & 15;
  const int qh = lane >> 4;
  const int NT = K / 256;  // 8

  for (int t = 0; t < NT; ++t) {
    const int k0 = t * 256;
#pragma unroll
    for (int p = 0; p < 4; ++p) {
#pragma unroll
      for (int c = 0; c < 2; ++c) {
        GLD_TO_LDS16(Ag + k0 + p * 64 + (size_t)(c * 8) * K,
                     sA[p] + dst + c * 512);
        GLD_TO_LDS16(Bg + k0 + p * 64 + (size_t)(c * 8) * K,
                     sB[p] + dst + c * 512);
      }
    }
    __syncthreads();

#pragma unroll
    for (int ks = 0; ks < 8; ++ks) {
      const int pnl = ks >> 1;
      const int q2 = (ks * 4 + qh) & 7;
      bf16x8 av[2], bv[2];
#pragma unroll
      for (int i = 0; i < 2; ++i) {
        const int ra = wm + i * 16 + fr;
        av[i] = *(const bf16x8*)(sA[pnl] + ra * 64 + ((q2 ^ (ra & 7)) * 8));
      }
#pragma unroll
      for (int j = 0; j < 2; ++j) {
        const int rb = wn + j * 16 + fr;
        bv[j] = *(const bf16x8*)(sB[pnl] + rb * 64 + ((q2 ^ (rb & 7)) * 8));
      }
#pragma unroll
      for (int i = 0; i < 2; ++i)
#pragma unroll
        for (int j = 0; j < 2; ++j)
          acc[i][j] = __builtin_amdgcn_mfma_f32_16x16x32_bf16(
              av[i], bv[j], acc[i][j], 0, 0, 0);
    }
    __syncthreads();
  }

  const int cm0 = qh * 4;
#pragma unroll
  for (int j = 0; j < 2; ++j) {
    const int gn = bn + wn + j * 16 + fr;
    const float bj = bias[gn];
#pragma unroll
    for (int i = 0; i < 2; ++i) {
#pragma unroll
      for (int r = 0; r < 4; ++r) {
        const int gm = bm + wm + i * 16 + cm0 + r;
        const float z =
            0.75f * (acc[i][j][r] + bj) + 0.125f * lbl[(size_t)gm * N + gn];
        out[(size_t)gm * N + gn] = 0.35f / (1.0f + __expf(-z));
      }
    }
  }
}

extern "C" void kernel_launch(void* const* d_in, const int* in_sizes, int n_in,
                              void* d_out, int out_size, void* d_ws, size_t ws_size,
                              hipStream_t stream) {
  constexpr int IN = 1024, HID = 2048, OUT = 512, B = 4096;
  const float* psp = (const float*)d_in[0];   // [IN, B]
  const float* lbl = (const float*)d_in[1];   // [B, OUT]
  const float* W_h = (const float*)d_in[2];   // [HID, IN]
  const float* b_h = (const float*)d_in[3];   // [HID]
  const float* W_o = (const float*)d_in[4];   // [OUT, HID]
  const float* b_o = (const float*)d_in[5];   // [OUT]
  float* out = (float*)d_out;                 // [B, OUT] fp32

  unsigned char* Whb8 = (unsigned char*)d_ws;            // [HID, IN] fp8, 2 MB
  bf16_t* Wob = (bf16_t*)(Whb8 + (size_t)HID * IN);      // [OUT, HID] bf16, 2 MB
  unsigned char* pspT8 = (unsigned char*)(Wob + (size_t)OUT * HID);  // 4 MB
  bf16_t* Rm = (bf16_t*)(pspT8 + (size_t)B * IN);        // [B, HID] bf16, 16 MB

  prep<<<1024, 256, 0, stream>>>(
      psp, pspT8, (const float4*)W_h, (int*)Whb8, (const float4*)W_o,
      (bf16x4v*)Wob);
  gemm1_nt<<<dim3(B / 128, HID / 128), 256, 0, stream>>>(
      pspT8, Whb8, b_h, Rm, B, HID, IN);
  gemm2_nt<<<dim3(B / 64, OUT / 64), 256, 0, stream>>>(
      Rm, Wob, b_o, lbl, out, B, OUT, HID);
}

// Round 10
// 114.576 us; speedup vs baseline: 1.1972x; 1.0235x over previous
//
#include <hip/hip_runtime.h>
#include <hip/hip_bf16.h>

// Net_27358941675610: the 50-step scan collapses to its fixed point:
//   R   = 0.35*sigmoid((6/7)*(psp^T @ W_h^T + b_h))            [4096,2048]
//   out = 0.35*sigmoid(0.75*(R @ W_o^T + b_o) + 0.125*label)   [4096,512]
// R25: R24 failed absmax by 0.7% (5.859e-3 vs 5.820e-3). Calibrated error
// model (F=10.5 from the R24 failure): extra = F * per-term RMS. Fixes:
//  (1) CENTER R: store D = R - 0.175 as fp8 (E|D|~0.064 vs E|R|~0.175,
//      rel-err dtype => 2.7x less error); exact compensation via
//      z = 0.75*(acc + 0.175*rowsum(W_q) + b), rowsum over the QUANTIZED
//      W (computed in prep, per-block partials, no atomics).
//  (2) SPLIT W_o = hi + lo fp8 (residual fits e4m3 subnormal range):
//      r*dw 2.6e-4 -> 5e-5. Per-term RMS 3.7e-4 -> 1.1e-4, predicted
//      total absmax ~3.1e-3 (45% margin).
// gemm2: A=D, B=Whi,Wlo; BK=256 (2x128B planes), NT=8, LDS 48KB,
//        2 blk/CU, grid (64,8)=512; 2 dependent MFMAs per k64-step.
// gemm1 = R23-proven, epilogue stores D=R-0.175 as fp8. prep adds W_o
// hi/lo + quantized rowsums (rs2[1024] partials, gemm2 sums pairs).

typedef __bf16 bf16_t;
typedef float f32x4 __attribute__((ext_vector_type(4)));
typedef float f32x16 __attribute__((ext_vector_type(16)));
typedef int i32x4 __attribute__((ext_vector_type(4)));
typedef int i32x8 __attribute__((ext_vector_type(8)));

#define GLD_TO_LDS16(gp, lp)                                            \
  __builtin_amdgcn_global_load_lds(                                     \
      (__attribute__((address_space(1))) void*)(void*)(gp),             \
      (__attribute__((address_space(3))) void*)(lp), 16, 0, 0)

__device__ inline int pk4_fp8(float x, float y, float z, float w) {
  int lo = __builtin_amdgcn_cvt_pk_fp8_f32(x, y, 0, false);   // bytes 0,1
  return __builtin_amdgcn_cvt_pk_fp8_f32(z, w, lo, true);     // bytes 2,3
}

__device__ inline unsigned char fp8_1(float x) {
  return (unsigned char)(__builtin_amdgcn_cvt_pk_fp8_f32(x, x, 0, false) & 0xFF);
}

// OCP e4m3fn decode (no NaN handling needed: |inputs| << 448)
__device__ inline float dec_e4m3(int b) {
  const int s = (b >> 7) & 1, e = (b >> 3) & 15, m = b & 7;
  const float v = e ? ldexpf((float)(8 + m), e - 10) : ldexpf((float)m, -9);
  return s ? -v : v;
}

// ---- prep: psp transpose->fp8, W_h->fp8, W_o->fp8 hi+lo + rowsums --------
__global__ __launch_bounds__(256) void prep(
    const float* __restrict__ psp, unsigned char* __restrict__ pspT8,
    const float4* __restrict__ wh, int* __restrict__ wh8,
    const float4* __restrict__ wo, int* __restrict__ wo8hi,
    int* __restrict__ wo8lo, float* __restrict__ rs2) {
  __shared__ float tile[64][65];
  __shared__ float red[256];
  const int tid = threadIdx.x;
  const int b = blockIdx.x;
  const int c0 = (b & 63) * 64;   // batch dim base
  const int r0 = (b >> 6) * 64;   // in dim base
  const int tx = tid & 63;
  const int ty = tid >> 6;
#pragma unroll
  for (int i = 0; i < 16; ++i) {
    const int r = ty + i * 4;
    tile[r][tx] = psp[(size_t)(r0 + r) * 4096 + c0 + tx];  // tile[in][batch]
  }
  // W_h -> fp8: 524288 float4 = 1024 blocks * 512 (2/thread)
  {
    const int i1 = b * 512 + tid;
#pragma unroll
    for (int u = 0; u < 2; ++u) {
      const int idx = i1 + u * 256;
      const float4 v = wh[idx];
      wh8[idx] = pk4_fp8(v.x, v.y, v.z, v.w);
    }
  }
  // W_o -> fp8 hi+lo: 262144 float4 = 1024 blocks * 256 (1/thread).
  // Block b covers elements [b*1024,(b+1)*1024) = half of row b/2.
  float psum;
  {
    const int i2 = b * 256 + tid;
    const float4 v = wo[i2];
    const int hi = pk4_fp8(v.x, v.y, v.z, v.w);
    const float hx = dec_e4m3(hi & 0xFF), hy = dec_e4m3((hi >> 8) & 0xFF);
    const float hz = dec_e4m3((hi >> 16) & 0xFF), hw = dec_e4m3((hi >> 24) & 0xFF);
    const int lo = pk4_fp8(v.x - hx, v.y - hy, v.z - hz, v.w - hw);
    wo8hi[i2] = hi;
    wo8lo[i2] = lo;
    psum = hx + hy + hz + hw + dec_e4m3(lo & 0xFF) + dec_e4m3((lo >> 8) & 0xFF) +
           dec_e4m3((lo >> 16) & 0xFF) + dec_e4m3((lo >> 24) & 0xFF);
  }
  red[tid] = psum;
  __syncthreads();
#pragma unroll
  for (int s = 128; s > 0; s >>= 1) {
    if (tid < s) red[tid] += red[tid + s];
    __syncthreads();
  }
  if (tid == 0) rs2[b] = red[0];  // partial rowsum of quantized W_o
  // transpose out as fp8: thread packs 4 consecutive in-dim elems
  const int brow0 = tid >> 4;
  const int c4 = (tid & 15) * 4;
#pragma unroll
  for (int i = 0; i < 4; ++i) {
    const int brow = brow0 + i * 16;
    const int packed = pk4_fp8(tile[c4][brow], tile[c4 + 1][brow],
                               tile[c4 + 2][brow], tile[c4 + 3][brow]);
    *(int*)(pspT8 + (size_t)(c0 + brow) * 1024 + r0 + c4) = packed;
  }
}

// ---- GEMM1: D(fp8) = 0.35*sigmoid(6/7*(A @ Bt^T + bias)) - 0.175 --------
// R23-proven. mfma_scale_f32_32x32x64_f8f6f4, unit scales. 128x128 tile,
// 4 waves of 64x64 (2x2 of 32x32). BK=256 fp8 as two 128B planes, NT=4.
// LDS 64KB single-buffer -> 2 blk/CU, grid (32,16)=512.
__global__ __launch_bounds__(256, 2) void gemm1_nt(
    const unsigned char* __restrict__ A8, const unsigned char* __restrict__ B8,
    const float* __restrict__ bias, unsigned char* __restrict__ C8,
    int M, int N, int K) {  // K = 1024 bytes/row
  __shared__ __align__(16) unsigned char sA[2][128 * 128];  // 2 planes x 16KB
  __shared__ __align__(16) unsigned char sB[2][128 * 128];

  const int tid = threadIdx.x;
  const int wave = tid >> 6;  // 0..3
  const int lane = tid & 63;
  const int bm = blockIdx.x * 128;
  const int bn = blockIdx.y * 128;
  const int wm = (wave & 1) * 64;
  const int wn = (wave >> 1) * 64;

  f32x16 acc[2][2] = {};

  const int srow8 = lane >> 3;
  const int gseg = (lane & 7) ^ srow8;  // pre-swizzled global 16B-segment
  const unsigned char* Ag =
      A8 + (size_t)(bm + wave * 32 + srow8) * 1024 + gseg * 16;
  const unsigned char* Bg =
      B8 + (size_t)(bn + wave * 32 + srow8) * 1024 + gseg * 16;
  const int dst = wave * 4096;  // 32 rows * 128 B per wave, per plane

  const int col = lane & 31;
  const int g = lane >> 5;

  for (int t = 0; t < 4; ++t) {  // NT = 1024/256
    const int kb = t * 256;
#pragma unroll
    for (int h = 0; h < 2; ++h) {     // half-K plane (128 B)
#pragma unroll
      for (int c = 0; c < 4; ++c) {   // 8-row chunks
        GLD_TO_LDS16(Ag + kb + h * 128 + (size_t)(c * 8) * 1024,
                     sA[h] + dst + c * 1024);
        GLD_TO_LDS16(Bg + kb + h * 128 + (size_t)(c * 8) * 1024,
                     sB[h] + dst + c * 1024);
      }
    }
    __syncthreads();

#pragma unroll
    for (int p = 0; p < 4; ++p) {  // k64-steps within BK=256
      const int h = p >> 1;
      const int s0 = (p & 1) * 4 + 2 * g;  // lane-group's first 16B segment
      i32x8 av[2], bv[2];
#pragma unroll
      for (int i = 0; i < 2; ++i) {
        const int rr = wm + i * 32 + col;
        const unsigned char* base = sA[h] + rr * 128;
        const i32x4 lo = *(const i32x4*)(base + ((s0 ^ (rr & 7)) * 16));
        const i32x4 hi = *(const i32x4*)(base + (((s0 + 1) ^ (rr & 7)) * 16));
        av[i] = __builtin_shufflevector(lo, hi, 0, 1, 2, 3, 4, 5, 6, 7);
      }
#pragma unroll
      for (int j = 0; j < 2; ++j) {
        const int rr = wn + j * 32 + col;
        const unsigned char* base = sB[h] + rr * 128;
        const i32x4 lo = *(const i32x4*)(base + ((s0 ^ (rr & 7)) * 16));
        const i32x4 hi = *(const i32x4*)(base + (((s0 + 1) ^ (rr & 7)) * 16));
        bv[j] = __builtin_shufflevector(lo, hi, 0, 1, 2, 3, 4, 5, 6, 7);
      }
      __builtin_amdgcn_s_setprio(1);
#pragma unroll
      for (int i = 0; i < 2; ++i)
#pragma unroll
        for (int j = 0; j < 2; ++j)
          acc[i][j] = __builtin_amdgcn_mfma_scale_f32_32x32x64_f8f6f4(
              av[i], bv[j], acc[i][j], 0, 0,          // cbsz=fp8, blgp=fp8
              0, 0x7F7F7F7F, 0, 0x7F7F7F7F);          // unit scales (2^0)
      __builtin_amdgcn_s_setprio(0);
    }
    __syncthreads();
  }

  // epilogue: col = lane&31, row = (r&3) + 8*(r>>2) + 4*(lane>>5) [m74/m101]
  const int rbase = 4 * g;
#pragma unroll
  for (int j = 0; j < 2; ++j) {
    const int gn = bn + wn + j * 32 + col;
    const float bj = bias[gn];
#pragma unroll
    for (int i = 0; i < 2; ++i) {
#pragma unroll
      for (int r = 0; r < 16; ++r) {
        const int gm = bm + wm + i * 32 + (r & 3) + 8 * (r >> 2) + rbase;
        const float z = 0.8571428571428571f * (acc[i][j][r] + bj);
        C8[(size_t)gm * N + gn] = fp8_1(0.35f / (1.0f + __expf(-z)) - 0.175f);
      }
    }
  }
}

// ---- GEMM2: out = 0.35*sigmoid(0.75*((D@W^T) + 0.175*rs + b) + .125*lbl) -
// MX-fp8, split-W: acc = D@(Whi+Wlo)^T via 2 MFMAs per k64-step.
// 64x64 tile, 4 waves of 32x32. BK=256 as two 128B planes, NT=8.
// LDS 48KB -> 2 blk/CU, grid (64,8)=512.
__global__ __launch_bounds__(256, 2) void gemm2_nt(
    const unsigned char* __restrict__ A8, const unsigned char* __restrict__ Bh8,
    const unsigned char* __restrict__ Bl8, const float* __restrict__ bias,
    const float* __restrict__ rs2, const float* __restrict__ lbl,
    float* __restrict__ out, int M, int N, int K) {  // K = 2048 bytes/row
  __shared__ __align__(16) unsigned char sA[2][64 * 128];   // 16 KB
  __shared__ __align__(16) unsigned char sBh[2][64 * 128];  // 16 KB
  __shared__ __align__(16) unsigned char sBl[2][64 * 128];  // 16 KB

  const int tid = threadIdx.x;
  const int wave = tid >> 6;
  const int lane = tid & 63;
  const int bm = blockIdx.x * 64;
  const int bn = blockIdx.y * 64;
  const int wm = (wave & 1) * 32;
  const int wn = (wave >> 1) * 32;

  f32x16 acc = {};

  const int srow8 = lane >> 3;
  const int gseg = (lane & 7) ^ srow8;
  const unsigned char* Ag =
      A8 + (size_t)(bm + wave * 16 + srow8) * 2048 + gseg * 16;
  const unsigned char* Bhg =
      Bh8 + (size_t)(bn + wave * 16 + srow8) * 2048 + gseg * 16;
  const unsigned char* Blg =
      Bl8 + (size_t)(bn + wave * 16 + srow8) * 2048 + gseg * 16;
  const int dst = wave * 2048;  // 16 rows * 128 B per wave, per plane

  const int col = lane & 31;
  const int g = lane >> 5;

  for (int t = 0; t < 8; ++t) {  // NT = 2048/256
    const int kb = t * 256;
#pragma unroll
    for (int h = 0; h < 2; ++h) {     // two 128B planes
#pragma unroll
      for (int c = 0; c < 2; ++c) {   // 8-row chunks (16 rows/wave)
        GLD_TO_LDS16(Ag + kb + h * 128 + (size_t)(c * 8) * 2048,
                     sA[h] + dst + c * 1024);
        GLD_TO_LDS16(Bhg + kb + h * 128 + (size_t)(c * 8) * 2048,
                     sBh[h] + dst + c * 1024);
        GLD_TO_LDS16(Blg + kb + h * 128 + (size_t)(c * 8) * 2048,
                     sBl[h] + dst + c * 1024);
      }
    }
    __syncthreads();

#pragma unroll
    for (int p = 0; p < 4; ++p) {  // k64-steps within BK=256
      const int h = p >> 1;
      const int s0 = (p & 1) * 4 + 2 * g;
      i32x8 av, bhv, blv;
      {
        const int rr = wm + col;
        const unsigned char* base = sA[h] + rr * 128;
        const i32x4 lo = *(const i32x4*)(base + ((s0 ^ (rr & 7)) * 16));
        const i32x4 hi = *(const i32x4*)(base + (((s0 + 1) ^ (rr & 7)) * 16));
        av = __builtin_shufflevector(lo, hi, 0, 1, 2, 3, 4, 5, 6, 7);
      }
      {
        const int rr = wn + col;
        const unsigned char* bb = sBh[h] + rr * 128;
        const i32x4 lo = *(const i32x4*)(bb + ((s0 ^ (rr & 7)) * 16));
        const i32x4 hi = *(const i32x4*)(bb + (((s0 + 1) ^ (rr & 7)) * 16));
        bhv = __builtin_shufflevector(lo, hi, 0, 1, 2, 3, 4, 5, 6, 7);
        const unsigned char* bl = sBl[h] + rr * 128;
        const i32x4 lo2 = *(const i32x4*)(bl + ((s0 ^ (rr & 7)) * 16));
        const i32x4 hi2 = *(const i32x4*)(bl + (((s0 + 1) ^ (rr & 7)) * 16));
        blv = __builtin_shufflevector(lo2, hi2, 0, 1, 2, 3, 4, 5, 6, 7);
      }
      __builtin_amdgcn_s_setprio(1);
      acc = __builtin_amdgcn_mfma_scale_f32_32x32x64_f8f6f4(
          av, bhv, acc, 0, 0, 0, 0x7F7F7F7F, 0, 0x7F7F7F7F);
      acc = __builtin_amdgcn_mfma_scale_f32_32x32x64_f8f6f4(
          av, blv, acc, 0, 0, 0, 0x7F7F7F7F, 0, 0x7F7F7F7F);
      __builtin_amdgcn_s_setprio(0);
    }
    __syncthreads();
  }

  // epilogue: col = lane&31, row = (r&3) + 8*(r>>2) + 4*(lane>>5) [m74/m101]
  const int rbase = 4 * g;
  const int gn = bn + wn + col;
  // basal_V_o = acc + 0.175*rowsum(W_q) + bias  (centering compensation)
  const float bj = bias[gn] + 0.175f * (rs2[2 * gn] + rs2[2 * gn + 1]);
#pragma unroll
  for (int r = 0; r < 16; ++r) {
    const int gm = bm + wm + (r & 3) + 8 * (r >> 2) + rbase;
    const float z = 0.75f * (acc[r] + bj) + 0.125f * lbl[(size_t)gm * N + gn];
    out[(size_t)gm * N + gn] = 0.35f / (1.0f + __expf(-z));
  }
}

extern "C" void kernel_launch(void* const* d_in, const int* in_sizes, int n_in,
                              void* d_out, int out_size, void* d_ws, size_t ws_size,
                              hipStream_t stream) {
  constexpr int IN = 1024, HID = 2048, OUT = 512, B = 4096;
  const float* psp = (const float*)d_in[0];   // [IN, B]
  const float* lbl = (const float*)d_in[1];   // [B, OUT]
  const float* W_h = (const float*)d_in[2];   // [HID, IN]
  const float* b_h = (const float*)d_in[3];   // [HID]
  const float* W_o = (const float*)d_in[4];   // [OUT, HID]
  const float* b_o = (const float*)d_in[5];   // [OUT]
  float* out = (float*)d_out;                 // [B, OUT] fp32

  unsigned char* Whb8 = (unsigned char*)d_ws;          // [HID, IN] fp8, 2 MB
  unsigned char* Wo8hi = Whb8 + (size_t)HID * IN;      // [OUT, HID] fp8, 1 MB
  unsigned char* Wo8lo = Wo8hi + (size_t)OUT * HID;    // [OUT, HID] fp8, 1 MB
  unsigned char* pspT8 = Wo8lo + (size_t)OUT * HID;    // [B, IN] fp8, 4 MB
  unsigned char* Dm8 = pspT8 + (size_t)B * IN;         // [B, HID] fp8, 8 MB
  float* rs2 = (float*)(Dm8 + (size_t)B * HID);        // [1024] partials, 4 KB

  prep<<<1024, 256, 0, stream>>>(
      psp, pspT8, (const float4*)W_h, (int*)Whb8, (const float4*)W_o,
      (int*)Wo8hi, (int*)Wo8lo, rs2);
  gemm1_nt<<<dim3(B / 128, HID / 128), 256, 0, stream>>>(
      pspT8, Whb8, b_h, Dm8, B, HID, IN);
  gemm2_nt<<<dim3(B / 64, OUT / 64), 256, 0, stream>>>(
      Dm8, Wo8hi, Wo8lo, b_o, rs2, lbl, out, B, OUT, HID);
}

// Round 12
// 109.673 us; speedup vs baseline: 1.2507x; 1.0447x over previous
//
#include <hip/hip_runtime.h>
#include <hip/hip_bf16.h>

// Net_27358941675610: the 50-step scan collapses to its fixed point:
//   R   = 0.35*sigmoid((6/7)*(psp^T @ W_h^T + b_h))            [4096,2048]
//   out = 0.35*sigmoid(0.75*(R @ W_o^T + b_o) + 0.125*label)   [4096,512]
// R27 = R26 resubmitted verbatim (R26 bench was an infra failure --
// "container failed twice" -- kernel never executed).
// R26: gemm2 slimmed. R25 validated the calibrated error model twice
// (R24 fail 5.86e-3, R25 pass 2.93e-3). Centering's compensation uses the
// QUANTIZED rowsum, so the 0.175*sum(w_q) term is exact and the lo-plane
// only protects the small D*dw term (1e-4/term). Dropping it: predicted
// extra 0.98e-3 * (1.4/1.1) => total ~3.2e-3, 45% margin. gemm2 reverts
// to R24's harness-proven BK=512/NT=4 4-plane geometry with single hi-W:
// staged 384->256 KB/block, MFMA/wave 64->32. gemm1 = R25 verbatim
// (MX-fp8, D=R-0.175 output). prep drops lo-plane work.

typedef __bf16 bf16_t;
typedef float f32x4 __attribute__((ext_vector_type(4)));
typedef float f32x16 __attribute__((ext_vector_type(16)));
typedef int i32x4 __attribute__((ext_vector_type(4)));
typedef int i32x8 __attribute__((ext_vector_type(8)));

#define GLD_TO_LDS16(gp, lp)                                            \
  __builtin_amdgcn_global_load_lds(                                     \
      (__attribute__((address_space(1))) void*)(void*)(gp),             \
      (__attribute__((address_space(3))) void*)(lp), 16, 0, 0)

__device__ inline int pk4_fp8(float x, float y, float z, float w) {
  int lo = __builtin_amdgcn_cvt_pk_fp8_f32(x, y, 0, false);   // bytes 0,1
  return __builtin_amdgcn_cvt_pk_fp8_f32(z, w, lo, true);     // bytes 2,3
}

__device__ inline unsigned char fp8_1(float x) {
  return (unsigned char)(__builtin_amdgcn_cvt_pk_fp8_f32(x, x, 0, false) & 0xFF);
}

// OCP e4m3fn decode (no NaN handling needed: |inputs| << 448)
__device__ inline float dec_e4m3(int b) {
  const int s = (b >> 7) & 1, e = (b >> 3) & 15, m = b & 7;
  const float v = e ? ldexpf((float)(8 + m), e - 10) : ldexpf((float)m, -9);
  return s ? -v : v;
}

// ---- prep: psp transpose->fp8, W_h->fp8, W_o->fp8 + quantized rowsums ----
__global__ __launch_bounds__(256) void prep(
    const float* __restrict__ psp, unsigned char* __restrict__ pspT8,
    const float4* __restrict__ wh, int* __restrict__ wh8,
    const float4* __restrict__ wo, int* __restrict__ wo8,
    float* __restrict__ rs2) {
  __shared__ float tile[64][65];
  __shared__ float red[256];
  const int tid = threadIdx.x;
  const int b = blockIdx.x;
  const int c0 = (b & 63) * 64;   // batch dim base
  const int r0 = (b >> 6) * 64;   // in dim base
  const int tx = tid & 63;
  const int ty = tid >> 6;
#pragma unroll
  for (int i = 0; i < 16; ++i) {
    const int r = ty + i * 4;
    tile[r][tx] = psp[(size_t)(r0 + r) * 4096 + c0 + tx];  // tile[in][batch]
  }
  // W_h -> fp8: 524288 float4 = 1024 blocks * 512 (2/thread)
  {
    const int i1 = b * 512 + tid;
#pragma unroll
    for (int u = 0; u < 2; ++u) {
      const int idx = i1 + u * 256;
      const float4 v = wh[idx];
      wh8[idx] = pk4_fp8(v.x, v.y, v.z, v.w);
    }
  }
  // W_o -> fp8 + quantized partial rowsum: 262144 float4 (1/thread).
  // Block b covers elements [b*1024,(b+1)*1024) = one half of row b/2.
  float psum;
  {
    const int i2 = b * 256 + tid;
    const float4 v = wo[i2];
    const int hi = pk4_fp8(v.x, v.y, v.z, v.w);
    wo8[i2] = hi;
    psum = dec_e4m3(hi & 0xFF) + dec_e4m3((hi >> 8) & 0xFF) +
           dec_e4m3((hi >> 16) & 0xFF) + dec_e4m3((hi >> 24) & 0xFF);
  }
  red[tid] = psum;
  __syncthreads();
#pragma unroll
  for (int s = 128; s > 0; s >>= 1) {
    if (tid < s) red[tid] += red[tid + s];
    __syncthreads();
  }
  if (tid == 0) rs2[b] = red[0];  // partial rowsum of quantized W_o
  // transpose out as fp8: thread packs 4 consecutive in-dim elems
  const int brow0 = tid >> 4;
  const int c4 = (tid & 15) * 4;
#pragma unroll
  for (int i = 0; i < 4; ++i) {
    const int brow = brow0 + i * 16;
    const int packed = pk4_fp8(tile[c4][brow], tile[c4 + 1][brow],
                               tile[c4 + 2][brow], tile[c4 + 3][brow]);
    *(int*)(pspT8 + (size_t)(c0 + brow) * 1024 + r0 + c4) = packed;
  }
}

// ---- GEMM1: D(fp8) = 0.35*sigmoid(6/7*(A @ Bt^T + bias)) - 0.175 --------
// R25-proven. mfma_scale_f32_32x32x64_f8f6f4, unit scales. 128x128 tile,
// 4 waves of 64x64 (2x2 of 32x32). BK=256 fp8 as two 128B planes, NT=4.
// LDS 64KB single-buffer -> 2 blk/CU, grid (32,16)=512.
__global__ __launch_bounds__(256, 2) void gemm1_nt(
    const unsigned char* __restrict__ A8, const unsigned char* __restrict__ B8,
    const float* __restrict__ bias, unsigned char* __restrict__ C8,
    int M, int N, int K) {  // K = 1024 bytes/row
  __shared__ __align__(16) unsigned char sA[2][128 * 128];  // 2 planes x 16KB
  __shared__ __align__(16) unsigned char sB[2][128 * 128];

  const int tid = threadIdx.x;
  const int wave = tid >> 6;  // 0..3
  const int lane = tid & 63;
  const int bm = blockIdx.x * 128;
  const int bn = blockIdx.y * 128;
  const int wm = (wave & 1) * 64;
  const int wn = (wave >> 1) * 64;

  f32x16 acc[2][2] = {};

  const int srow8 = lane >> 3;
  const int gseg = (lane & 7) ^ srow8;  // pre-swizzled global 16B-segment
  const unsigned char* Ag =
      A8 + (size_t)(bm + wave * 32 + srow8) * 1024 + gseg * 16;
  const unsigned char* Bg =
      B8 + (size_t)(bn + wave * 32 + srow8) * 1024 + gseg * 16;
  const int dst = wave * 4096;  // 32 rows * 128 B per wave, per plane

  const int col = lane & 31;
  const int g = lane >> 5;

  for (int t = 0; t < 4; ++t) {  // NT = 1024/256
    const int kb = t * 256;
#pragma unroll
    for (int h = 0; h < 2; ++h) {     // half-K plane (128 B)
#pragma unroll
      for (int c = 0; c < 4; ++c) {   // 8-row chunks
        GLD_TO_LDS16(Ag + kb + h * 128 + (size_t)(c * 8) * 1024,
                     sA[h] + dst + c * 1024);
        GLD_TO_LDS16(Bg + kb + h * 128 + (size_t)(c * 8) * 1024,
                     sB[h] + dst + c * 1024);
      }
    }
    __syncthreads();

#pragma unroll
    for (int p = 0; p < 4; ++p) {  // k64-steps within BK=256
      const int h = p >> 1;
      const int s0 = (p & 1) * 4 + 2 * g;  // lane-group's first 16B segment
      i32x8 av[2], bv[2];
#pragma unroll
      for (int i = 0; i < 2; ++i) {
        const int rr = wm + i * 32 + col;
        const unsigned char* base = sA[h] + rr * 128;
        const i32x4 lo = *(const i32x4*)(base + ((s0 ^ (rr & 7)) * 16));
        const i32x4 hi = *(const i32x4*)(base + (((s0 + 1) ^ (rr & 7)) * 16));
        av[i] = __builtin_shufflevector(lo, hi, 0, 1, 2, 3, 4, 5, 6, 7);
      }
#pragma unroll
      for (int j = 0; j < 2; ++j) {
        const int rr = wn + j * 32 + col;
        const unsigned char* base = sB[h] + rr * 128;
        const i32x4 lo = *(const i32x4*)(base + ((s0 ^ (rr & 7)) * 16));
        const i32x4 hi = *(const i32x4*)(base + (((s0 + 1) ^ (rr & 7)) * 16));
        bv[j] = __builtin_shufflevector(lo, hi, 0, 1, 2, 3, 4, 5, 6, 7);
      }
      __builtin_amdgcn_s_setprio(1);
#pragma unroll
      for (int i = 0; i < 2; ++i)
#pragma unroll
        for (int j = 0; j < 2; ++j)
          acc[i][j] = __builtin_amdgcn_mfma_scale_f32_32x32x64_f8f6f4(
              av[i], bv[j], acc[i][j], 0, 0,          // cbsz=fp8, blgp=fp8
              0, 0x7F7F7F7F, 0, 0x7F7F7F7F);          // unit scales (2^0)
      __builtin_amdgcn_s_setprio(0);
    }
    __syncthreads();
  }

  // epilogue: col = lane&31, row = (r&3) + 8*(r>>2) + 4*(lane>>5) [m74/m101]
  const int rbase = 4 * g;
#pragma unroll
  for (int j = 0; j < 2; ++j) {
    const int gn = bn + wn + j * 32 + col;
    const float bj = bias[gn];
#pragma unroll
    for (int i = 0; i < 2; ++i) {
#pragma unroll
      for (int r = 0; r < 16; ++r) {
        const int gm = bm + wm + i * 32 + (r & 3) + 8 * (r >> 2) + rbase;
        const float z = 0.8571428571428571f * (acc[i][j][r] + bj);
        C8[(size_t)gm * N + gn] = fp8_1(0.35f / (1.0f + __expf(-z)) - 0.175f);
      }
    }
  }
}

// ---- GEMM2: out = 0.35*sigmoid(0.75*((D@W^T) + 0.175*rs + b) + .125*lbl) -
// MX-fp8, single hi-plane W (centering compensation is exact in the
// constant term). R24-proven geometry: 64x64 tile, 4 waves of 32x32,
// BK=512 as four 128B planes, NT=4. LDS 64KB -> 2 blk/CU, grid (64,8)=512.
__global__ __launch_bounds__(256, 2) void gemm2_nt(
    const unsigned char* __restrict__ A8, const unsigned char* __restrict__ B8,
    const float* __restrict__ bias, const float* __restrict__ rs2,
    const float* __restrict__ lbl, float* __restrict__ out,
    int M, int N, int K) {  // K = 2048 bytes/row
  __shared__ __align__(16) unsigned char sA[4][64 * 128];  // 4 planes x 8KB
  __shared__ __align__(16) unsigned char sB[4][64 * 128];

  const int tid = threadIdx.x;
  const int wave = tid >> 6;
  const int lane = tid & 63;
  const int bm = blockIdx.x * 64;
  const int bn = blockIdx.y * 64;
  const int wm = (wave & 1) * 32;
  const int wn = (wave >> 1) * 32;

  f32x16 acc = {};

  const int srow8 = lane >> 3;
  const int gseg = (lane & 7) ^ srow8;
  const unsigned char* Ag =
      A8 + (size_t)(bm + wave * 16 + srow8) * 2048 + gseg * 16;
  const unsigned char* Bg =
      B8 + (size_t)(bn + wave * 16 + srow8) * 2048 + gseg * 16;
  const int dst = wave * 2048;  // 16 rows * 128 B per wave, per plane

  const int col = lane & 31;
  const int g = lane >> 5;

  for (int t = 0; t < 4; ++t) {  // NT = 2048/512
    const int kb = t * 512;
#pragma unroll
    for (int h = 0; h < 4; ++h) {     // four 128B planes
#pragma unroll
      for (int c = 0; c < 2; ++c) {   // 8-row chunks (16 rows/wave)
        GLD_TO_LDS16(Ag + kb + h * 128 + (size_t)(c * 8) * 2048,
                     sA[h] + dst + c * 1024);
        GLD_TO_LDS16(Bg + kb + h * 128 + (size_t)(c * 8) * 2048,
                     sB[h] + dst + c * 1024);
      }
    }
    __syncthreads();

#pragma unroll
    for (int p = 0; p < 8; ++p) {  // k64-steps within BK=512
      const int h = p >> 1;
      const int s0 = (p & 1) * 4 + 2 * g;
      i32x8 av, bv;
      {
        const int rr = wm + col;
        const unsigned char* base = sA[h] + rr * 128;
        const i32x4 lo = *(const i32x4*)(base + ((s0 ^ (rr & 7)) * 16));
        const i32x4 hi = *(const i32x4*)(base + (((s0 + 1) ^ (rr & 7)) * 16));
        av = __builtin_shufflevector(lo, hi, 0, 1, 2, 3, 4, 5, 6, 7);
      }
      {
        const int rr = wn + col;
        const unsigned char* base = sB[h] + rr * 128;
        const i32x4 lo = *(const i32x4*)(base + ((s0 ^ (rr & 7)) * 16));
        const i32x4 hi = *(const i32x4*)(base + (((s0 + 1) ^ (rr & 7)) * 16));
        bv = __builtin_shufflevector(lo, hi, 0, 1, 2, 3, 4, 5, 6, 7);
      }
      __builtin_amdgcn_s_setprio(1);
      acc = __builtin_amdgcn_mfma_scale_f32_32x32x64_f8f6f4(
          av, bv, acc, 0, 0, 0, 0x7F7F7F7F, 0, 0x7F7F7F7F);
      __builtin_amdgcn_s_setprio(0);
    }
    __syncthreads();
  }

  // epilogue: col = lane&31, row = (r&3) + 8*(r>>2) + 4*(lane>>5) [m74/m101]
  const int rbase = 4 * g;
  const int gn = bn + wn + col;
  // basal_V_o = acc + 0.175*rowsum(W_q) + bias  (centering compensation)
  const float bj = bias[gn] + 0.175f * (rs2[2 * gn] + rs2[2 * gn + 1]);
#pragma unroll
  for (int r = 0; r < 16; ++r) {
    const int gm = bm + wm + (r & 3) + 8 * (r >> 2) + rbase;
    const float z = 0.75f * (acc[r] + bj) + 0.125f * lbl[(size_t)gm * N + gn];
    out[(size_t)gm * N + gn] = 0.35f / (1.0f + __expf(-z));
  }
}

extern "C" void kernel_launch(void* const* d_in, const int* in_sizes, int n_in,
                              void* d_out, int out_size, void* d_ws, size_t ws_size,
                              hipStream_t stream) {
  constexpr int IN = 1024, HID = 2048, OUT = 512, B = 4096;
  const float* psp = (const float*)d_in[0];   // [IN, B]
  const float* lbl = (const float*)d_in[1];   // [B, OUT]
  const float* W_h = (const float*)d_in[2];   // [HID, IN]
  const float* b_h = (const float*)d_in[3];   // [HID]
  const float* W_o = (const float*)d_in[4];   // [OUT, HID]
  const float* b_o = (const float*)d_in[5];   // [OUT]
  float* out = (float*)d_out;                 // [B, OUT] fp32

  unsigned char* Whb8 = (unsigned char*)d_ws;          // [HID, IN] fp8, 2 MB
  unsigned char* Wo8 = Whb8 + (size_t)HID * IN;        // [OUT, HID] fp8, 1 MB
  unsigned char* pspT8 = Wo8 + (size_t)OUT * HID;      // [B, IN] fp8, 4 MB
  unsigned char* Dm8 = pspT8 + (size_t)B * IN;         // [B, HID] fp8, 8 MB
  float* rs2 = (float*)(Dm8 + (size_t)B * HID);        // [1024] partials, 4 KB

  prep<<<1024, 256, 0, stream>>>(
      psp, pspT8, (const float4*)W_h, (int*)Whb8, (const float4*)W_o,
      (int*)Wo8, rs2);
  gemm1_nt<<<dim3(B / 128, HID / 128), 256, 0, stream>>>(
      pspT8, Whb8, b_h, Dm8, B, HID, IN);
  gemm2_nt<<<dim3(B / 64, OUT / 64), 256, 0, stream>>>(
      Dm8, Wo8, b_o, rs2, lbl, out, B, OUT, HID);
}